// Round 8
// baseline (571.299 us; speedup 1.0000x reference)
//
#include <hip/hip_runtime.h>
#include <math.h>
#include <stdint.h>

typedef __attribute__((ext_vector_type(8))) short bf16x8;
typedef __attribute__((ext_vector_type(4))) float floatx4;

static __device__ __forceinline__ unsigned short f32_to_bf16_rne(float f) {
    union { float f; uint32_t u; } v; v.f = f;
    uint32_t u = v.u;
    return (unsigned short)((u + 0x7fffu + ((u >> 16) & 1u)) >> 16);
}
static __device__ __forceinline__ float bf16_to_f32(unsigned short h) {
    union { uint32_t u; float f; } v; v.u = ((uint32_t)h) << 16;
    return v.f;
}
static __device__ __forceinline__ uint32_t pack2(float2 a) {
    return (uint32_t)f32_to_bf16_rne(a.x) | ((uint32_t)f32_to_bf16_rne(a.y) << 16);
}

// LDS-correct barrier that does NOT drain vmcnt (keeps global prefetch in
// flight across it). lgkmcnt(0) makes this wave's ds_writes visible.
#define BAR() do { \
    asm volatile("s_waitcnt lgkmcnt(0)" ::: "memory"); \
    __builtin_amdgcn_s_barrier(); \
    asm volatile("" ::: "memory"); } while (0)

// ---------------------------------------------------------------------------
// Prep: W1a (50x318) -> hi/lo bf16, fragment-ordered:
// byte = ks*8192 + p*4096 + kq*1024 + n*16  (n in [0,64), zero-padded)
// ---------------------------------------------------------------------------
__global__ void prep_w(const float* __restrict__ W1a, unsigned short* __restrict__ Bpre) {
    int idx = blockIdx.x * 256 + threadIdx.x;
    if (idx >= 40960) return;
    int e  = idx & 7;
    int n  = (idx >> 3) & 63;
    int kq = (idx >> 9) & 3;
    int p  = (idx >> 11) & 1;
    int ks = idx >> 12;
    int k  = ks * 32 + kq * 8 + e;
    float w = (n < 50 && k < 318) ? W1a[n * 318 + k] : 0.0f;
    unsigned short hi = f32_to_bf16_rne(w);
    Bpre[idx] = (p == 0) ? hi : f32_to_bf16_rne(w - bf16_to_f32(hi));
}

// ---------------------------------------------------------------------------
// Kernel A (persistent, 3 blocks/CU): grid 768, 256 threads, grid-stride over
// 8192 slabs (64 tokens each). Per iteration: pack prefetched regs -> plane,
// issue next loads (survive raw barriers), B hi/lo frags re-loaded per plane
// from L2-hot Bpre (40 VGPR transient), 80 MFMA, parallel tail. LDS 43008 B:
// planes @0/@21504; h1 overlays plane0 (stride 55), h2 plane1 (21),
// h3 plane0 (21). 6 non-draining barriers/iter.
// ---------------------------------------------------------------------------
#define A_STR 336
#define PLANE 21504
#define H1S 55
#define HSS 21
#define SLAB (64 * 318)
#define NSLAB 8192
#define GRID 768

#define LOADA(sl, PK) { \
    const float* sp_ = x + (size_t)(sl) * SLAB; \
    _Pragma("unroll") for (int j = 0; j < 20; ++j) { \
        int f_ = j * 256 + tid; int r_ = f_ / 80, c_ = f_ - r_ * 80; \
        bool pad_ = ((PK) == 160) && (c_ == 79); \
        ga[j] = pad_ ? make_float2(0.f, 0.f) \
                     : *(const float2*)(sp_ + r_ * 318 + (PK) + 2 * c_); } }

#define PACK(PL) { \
    _Pragma("unroll") for (int j = 0; j < 20; ++j) { \
        int f_ = j * 256 + tid; int r_ = f_ / 80, c_ = f_ - r_ * 80; \
        *(uint32_t*)(smem + (PL) * PLANE + r_ * A_STR + c_ * 4) = pack2(ga[j]); } }

#define LOADB(BH, BL, PL) { \
    const char* bb_ = (const char*)Bpre + (size_t)(PL) * 40960 \
                    + (kq << 10) + ((wv * 16 + fr) << 4); \
    _Pragma("unroll") for (int ks_ = 0; ks_ < 5; ++ks_) { \
        BH[ks_] = *(const bf16x8*)(bb_ + ks_ * 8192); \
        BL[ks_] = *(const bf16x8*)(bb_ + ks_ * 8192 + 4096); } }

#define MFMA_PLANE(PL, BH, BL) { \
    const char* ab_ = smem + (PL) * PLANE + fr * A_STR + kq * 16; \
    _Pragma("unroll") for (int ksl = 0; ksl < 5; ++ksl) \
        _Pragma("unroll") for (int mi = 0; mi < 4; ++mi) { \
            bf16x8 a_ = *(const bf16x8*)(ab_ + mi * (16 * A_STR) + ksl * 64); \
            acc[mi] = __builtin_amdgcn_mfma_f32_16x16x32_bf16(a_, BH[ksl], acc[mi], 0, 0, 0); \
            acc[mi] = __builtin_amdgcn_mfma_f32_16x16x32_bf16(a_, BL[ksl], acc[mi], 0, 0, 0); } }

__global__ __launch_bounds__(256, 3)
void fused_mlp(const float* __restrict__ x,
               const unsigned short* __restrict__ Bpre,
               const float* __restrict__ b1a,
               const float* __restrict__ W1b, const float* __restrict__ b1b,
               const float* __restrict__ W1c, const float* __restrict__ b1c,
               const float* __restrict__ pW1, const float* __restrict__ pb1,
               const float* __restrict__ pW2, const float* __restrict__ pb2,
               float* __restrict__ partials)
{
    __shared__ __align__(16) char smem[2 * PLANE];   // 43008 B

    const int tid  = threadIdx.x;
    const int wv   = tid >> 6;
    const int lane = tid & 63;
    const int fr   = lane & 15;
    const int kq   = lane >> 4;

    float2 ga[20];
    LOADA(blockIdx.x, 0);                 // prologue: slab0 plane0 in flight

    #pragma unroll 1
    for (int slab = blockIdx.x; slab < NSLAB; slab += GRID) {
        // ---- S0: pack plane0 (waits vmcnt via reg deps), issue p1 + B0 loads
        PACK(0);
        LOADA(slab, 160);
        bf16x8 Bh0[5], Bl0[5];
        LOADB(Bh0, Bl0, 0);
        BAR();                            // plane0 ready

        floatx4 acc[4];
        #pragma unroll
        for (int mi = 0; mi < 4; ++mi) acc[mi] = (floatx4){0.f, 0.f, 0.f, 0.f};
        MFMA_PLANE(0, Bh0, Bl0);

        // ---- pack plane1, issue next-slab p0 + B1 loads
        PACK(1);
        if (slab + GRID < NSLAB) LOADA(slab + GRID, 0);
        bf16x8 Bh1[5], Bl1[5];
        LOADB(Bh1, Bl1, 1);
        BAR();                            // plane1 ready; all p0 reads done
        MFMA_PLANE(1, Bh1, Bl1);

        // ---- S3: bias + ReLU -> h1 [64][55] f32 @ plane0 (p0 dead)
        {
            const int n = wv * 16 + fr;
            float* h1 = (float*)smem;
            if (n < 50) {
                float bia = b1a[n];
                #pragma unroll
                for (int mi = 0; mi < 4; ++mi)
                    #pragma unroll
                    for (int r = 0; r < 4; ++r)
                        h1[(mi * 16 + kq * 4 + r) * H1S + n] =
                            fmaxf(acc[mi][r] + bia, 0.0f);
            }
        }
        BAR();                            // h1 ready; all p1 reads done

        // ---- S4: layer2 (50->20), wave w -> outputs [5w,5w+5); h2 @ plane1
        {
            const float* h1r = (const float*)smem + lane * H1S;
            float* h2b = (float*)(smem + PLANE);
            #pragma unroll
            for (int oo = 0; oo < 5; ++oo) {
                int o = wv * 5 + oo;
                float a = b1b[o];
                const float* w = W1b + o * 50;
                #pragma unroll
                for (int i = 0; i < 50; ++i) a = fmaf(h1r[i], w[i], a);
                h2b[lane * HSS + o] = fmaxf(a, 0.0f);
            }
        }
        BAR();                            // h2 ready; h1 reads done

        // ---- S5: layer3 (20->20), wave w -> outputs [5w,5w+5); h3 @ plane0
        {
            const float* h2r = (const float*)(smem + PLANE) + lane * HSS;
            float* h3b = (float*)smem;
            #pragma unroll
            for (int oo = 0; oo < 5; ++oo) {
                int o = wv * 5 + oo;
                float a = b1c[o];
                const float* w = W1c + o * 20;
                #pragma unroll
                for (int i = 0; i < 20; ++i) a = fmaf(h2r[i], w[i], a);
                h3b[lane * HSS + o] = fmaxf(a, 0.0f);
            }
        }
        BAR();                            // h3 ready

        // ---- S6: all waves redundant: score + softmax partial; wv0 writes
        {
            float h3v[20];
            const float2* h3r = (const float2*)((const float*)smem + lane * HSS);
            #pragma unroll
            for (int i2 = 0; i2 < 10; ++i2) {
                float2 u = h3r[i2];
                h3v[2 * i2] = u.x; h3v[2 * i2 + 1] = u.y;
            }
            float s = pb2[0];
            #pragma unroll
            for (int j = 0; j < 10; ++j) {
                float a = pb1[j];
                const float* w = pW1 + j * 20;
                #pragma unroll
                for (int i = 0; i < 20; ++i) a = fmaf(h3v[i], w[i], a);
                s = fmaf(fmaxf(a, 0.0f), pW2[j], s);
            }

            float m = s;
            #pragma unroll
            for (int d = 32; d > 0; d >>= 1) m = fmaxf(m, __shfl_xor(m, d));
            float e = expf(s - m);
            float S = e;
            #pragma unroll
            for (int d = 32; d > 0; d >>= 1) S += __shfl_xor(S, d);

            float V[20];
            #pragma unroll
            for (int o = 0; o < 20; ++o) {
                float v = e * h3v[o];
                #pragma unroll
                for (int d = 32; d > 0; d >>= 1) v += __shfl_xor(v, d);
                V[o] = v;
            }

            if (wv == 0) {
                float myv = m;
                if (lane == 1) myv = S;
                #pragma unroll
                for (int o = 0; o < 20; ++o) if (lane == o + 2) myv = V[o];
                if (lane < 22) partials[(size_t)slab * 24 + lane] = myv;
            }
        }
        BAR();                            // h3 reads done before next pack
    }
}

// ---------------------------------------------------------------------------
// Kernel B: combine half-group partials, pool over G=128, normalize, head.
// ---------------------------------------------------------------------------
__global__ __launch_bounds__(128, 4)
void pool_g_head(const float* __restrict__ partials,
                 const float* __restrict__ qW1, const float* __restrict__ qb1,
                 const float* __restrict__ qW2, const float* __restrict__ qb2,
                 const float* __restrict__ W3a, const float* __restrict__ b3a,
                 const float* __restrict__ W3b, const float* __restrict__ b3b,
                 float* __restrict__ out)
{
    __shared__ float red_m[2];
    __shared__ float red_s[2];
    __shared__ float part[2][20];

    const int tid = threadIdx.x;      // g
    const int b = blockIdx.x;
    const float* P = partials + ((size_t)(b * 128 + tid)) * 48;

    float m0 = P[0], S0 = P[1], m1 = P[24], S1 = P[25];
    float m = fmaxf(m0, m1);
    float w0 = expf(m0 - m), w1 = expf(m1 - m);
    float den = fmaf(S0, w0, S1 * w1);

    float v[20];
    #pragma unroll
    for (int o = 0; o < 20; ++o)
        v[o] = fmaf(P[2 + o], w0, P[26 + o] * w1) / den;

    float s = qb2[0];
    #pragma unroll
    for (int j = 0; j < 10; ++j) {
        float a = qb1[j];
        const float* w = qW1 + j * 20;
        #pragma unroll
        for (int i = 0; i < 20; ++i) a = fmaf(v[i], w[i], a);
        s = fmaf(fmaxf(a, 0.0f), qW2[j], s);
    }

    const int wig = tid >> 6, lane = tid & 63;
    float mm = s;
    #pragma unroll
    for (int d = 32; d > 0; d >>= 1) mm = fmaxf(mm, __shfl_xor(mm, d));
    if (lane == 0) red_m[wig] = mm;
    __syncthreads();
    mm = fmaxf(red_m[0], red_m[1]);

    float e = expf(s - mm);
    float su = e;
    #pragma unroll
    for (int d = 32; d > 0; d >>= 1) su += __shfl_xor(su, d);
    if (lane == 0) red_s[wig] = su;

    #pragma unroll
    for (int o = 0; o < 20; ++o) {
        float val = e * v[o];
        #pragma unroll
        for (int d = 32; d > 0; d >>= 1) val += __shfl_xor(val, d);
        if (lane == 0) part[wig][o] = val;
    }
    __syncthreads();

    if (tid == 0) {
        float dg = red_s[0] + red_s[1];
        float rb[20];
        float n2 = 0.0f;
        #pragma unroll
        for (int o = 0; o < 20; ++o) {
            rb[o] = (part[0][o] + part[1][o]) / dg;
            n2 = fmaf(rb[o], rb[o], n2);
        }
        float nrm = fmaxf(sqrtf(n2), 1e-12f);
        #pragma unroll
        for (int o = 0; o < 20; ++o) rb[o] /= nrm;

        float accv = b3b[0];
        #pragma unroll
        for (int j = 0; j < 10; ++j) {
            float a = b3a[j];
            const float* w = W3a + j * 20;
            #pragma unroll
            for (int i = 0; i < 20; ++i) a = fmaf(rb[i], w[i], a);
            accv = fmaf(fmaxf(a, 0.0f), W3b[j], accv);
        }
        out[b] = accv;
    }
}

extern "C" void kernel_launch(void* const* d_in, const int* in_sizes, int n_in,
                              void* d_out, int out_size, void* d_ws, size_t ws_size,
                              hipStream_t stream) {
    const float* x   = (const float*)d_in[0];
    const float* W1a = (const float*)d_in[1];
    const float* b1a = (const float*)d_in[2];
    const float* W1b = (const float*)d_in[3];
    const float* b1b = (const float*)d_in[4];
    const float* W1c = (const float*)d_in[5];
    const float* b1c = (const float*)d_in[6];
    const float* pW1 = (const float*)d_in[7];
    const float* pb1 = (const float*)d_in[8];
    const float* pW2 = (const float*)d_in[9];
    const float* pb2 = (const float*)d_in[10];
    const float* qW1 = (const float*)d_in[11];
    const float* qb1 = (const float*)d_in[12];
    const float* qW2 = (const float*)d_in[13];
    const float* qb2 = (const float*)d_in[14];
    const float* W3a = (const float*)d_in[15];
    const float* b3a = (const float*)d_in[16];
    const float* W3b = (const float*)d_in[17];
    const float* b3b = (const float*)d_in[18];

    float* partials      = (float*)d_ws;                             // 786,432 B
    unsigned short* Bpre = (unsigned short*)((char*)d_ws + 786432);  // 81,920 B

    prep_w<<<160, 256, 0, stream>>>(W1a, Bpre);
    fused_mlp<<<GRID, 256, 0, stream>>>(
        x, Bpre, b1a, W1b, b1b, W1c, b1c, pW1, pb1, pW2, pb2, partials);
    pool_g_head<<<32, 128, 0, stream>>>(
        partials, qW1, qb1, qW2, qb2, W3a, b3a, W3b, b3b, (float*)d_out);
}

// Round 9
// 353.564 us; speedup vs baseline: 1.6158x; 1.6158x over previous
//
#include <hip/hip_runtime.h>
#include <math.h>
#include <stdint.h>

typedef __attribute__((ext_vector_type(8))) short bf16x8;
typedef __attribute__((ext_vector_type(4))) float floatx4;

static __device__ __forceinline__ unsigned short f32_to_bf16_rne(float f) {
    union { float f; uint32_t u; } v; v.f = f;
    uint32_t u = v.u;
    return (unsigned short)((u + 0x7fffu + ((u >> 16) & 1u)) >> 16);
}
static __device__ __forceinline__ float bf16_to_f32(unsigned short h) {
    union { uint32_t u; float f; } v; v.u = ((uint32_t)h) << 16;
    return v.f;
}
static __device__ __forceinline__ uint32_t pack2(float2 a) {
    return (uint32_t)f32_to_bf16_rne(a.x) | ((uint32_t)f32_to_bf16_rne(a.y) << 16);
}

// LDS-correct barrier that does NOT drain vmcnt: in-flight global prefetch
// survives. lgkmcnt(0) makes this wave's ds ops visible before the barrier.
#define BAR() do { \
    asm volatile("s_waitcnt lgkmcnt(0)" ::: "memory"); \
    __builtin_amdgcn_s_barrier(); \
    asm volatile("" ::: "memory"); } while (0)

// ---------------------------------------------------------------------------
// Prep: W1a (50x318) -> hi/lo bf16, fragment-ordered:
// byte = ks*8192 + p*4096 + kq*1024 + n*16  (n in [0,64), zero-padded)
// ---------------------------------------------------------------------------
__global__ void prep_w(const float* __restrict__ W1a, unsigned short* __restrict__ Bpre) {
    int idx = blockIdx.x * 256 + threadIdx.x;
    if (idx >= 40960) return;
    int e  = idx & 7;
    int n  = (idx >> 3) & 63;
    int kq = (idx >> 9) & 3;
    int p  = (idx >> 11) & 1;
    int ks = idx >> 12;
    int k  = ks * 32 + kq * 8 + e;
    float w = (n < 50 && k < 318) ? W1a[n * 318 + k] : 0.0f;
    unsigned short hi = f32_to_bf16_rne(w);
    Bpre[idx] = (p == 0) ? hi : f32_to_bf16_rne(w - bf16_to_f32(hi));
}

// ---------------------------------------------------------------------------
// Kernel A: 8192 blocks, 1 slab (64 tokens) each, 256 threads, 4 blocks/CU.
// Single 21.5KB A-plane, two sequential K-halves; B hi/lo frags transient
// (40 VGPR) from L2-hot Bpre. Raw barriers keep half-1 x-loads in flight
// under half-0 MFMAs. Tail: h1->LDS, then full per-thread layer2/3 + score
// + 64-token softmax partial (4 waves redundant, wv0 writes).
// ---------------------------------------------------------------------------
#define A_STR 336
#define H1S 55
#define SLAB (64 * 318)

#define LOADA(PK) { \
    _Pragma("unroll") for (int j = 0; j < 20; ++j) { \
        int f_ = j * 256 + tid; int r_ = f_ / 80, c_ = f_ - r_ * 80; \
        bool pad_ = ((PK) == 160) && (c_ == 79); \
        ga[j] = pad_ ? make_float2(0.f, 0.f) \
                     : *(const float2*)(slab + r_ * 318 + (PK) + 2 * c_); } }

#define PACK() { \
    _Pragma("unroll") for (int j = 0; j < 20; ++j) { \
        int f_ = j * 256 + tid; int r_ = f_ / 80, c_ = f_ - r_ * 80; \
        *(uint32_t*)(smem + r_ * A_STR + c_ * 4) = pack2(ga[j]); } }

#define LOADB(PL) { \
    const char* bb_ = (const char*)Bpre + (PL) * 40960 \
                    + (kq << 10) + ((wv * 16 + fr) << 4); \
    _Pragma("unroll") for (int ks_ = 0; ks_ < 5; ++ks_) { \
        Bh[ks_] = *(const bf16x8*)(bb_ + ks_ * 8192); \
        Bl[ks_] = *(const bf16x8*)(bb_ + ks_ * 8192 + 4096); } }

#define MFMA_PLANE() { \
    const char* ab_ = smem + fr * A_STR + kq * 16; \
    _Pragma("unroll") for (int ksl = 0; ksl < 5; ++ksl) \
        _Pragma("unroll") for (int mi = 0; mi < 4; ++mi) { \
            bf16x8 a_ = *(const bf16x8*)(ab_ + mi * (16 * A_STR) + ksl * 64); \
            acc[mi] = __builtin_amdgcn_mfma_f32_16x16x32_bf16(a_, Bh[ksl], acc[mi], 0, 0, 0); \
            acc[mi] = __builtin_amdgcn_mfma_f32_16x16x32_bf16(a_, Bl[ksl], acc[mi], 0, 0, 0); } }

__global__ __launch_bounds__(256, 4)
void fused_mlp(const float* __restrict__ x,
               const unsigned short* __restrict__ Bpre,
               const float* __restrict__ b1a,
               const float* __restrict__ W1b, const float* __restrict__ b1b,
               const float* __restrict__ W1c, const float* __restrict__ b1c,
               const float* __restrict__ pW1, const float* __restrict__ pb1,
               const float* __restrict__ pW2, const float* __restrict__ pb2,
               float* __restrict__ partials)
{
    __shared__ __align__(16) char smem[21504];

    const int tid  = threadIdx.x;
    const int wv   = tid >> 6;
    const int lane = tid & 63;
    const int fr   = lane & 15;
    const int kq   = lane >> 4;

    const float* slab = x + (size_t)blockIdx.x * SLAB;

    float2 ga[20];
    bf16x8 Bh[5], Bl[5];

    // ---- GEMM phase: two K-halves through one plane
    LOADA(0);
    LOADB(0);
    PACK();                // waits ga (half0) via reg deps
    LOADA(160);            // half1 x-loads in flight across BAR+MFMA
    BAR();                 // plane (half0) ready

    floatx4 acc[4];
    #pragma unroll
    for (int mi = 0; mi < 4; ++mi) acc[mi] = (floatx4){0.f, 0.f, 0.f, 0.f};
    MFMA_PLANE();          // half0
    BAR();                 // all plane reads done

    PACK();                // half1 (waits ga)
    LOADB(1);
    BAR();                 // plane (half1) ready
    MFMA_PLANE();          // half1
    BAR();                 // all plane reads done before h1 overwrite

    // ---- bias + ReLU -> h1 [64][55] f32 (overlays plane)
    {
        const int n = wv * 16 + fr;
        float* h1 = (float*)smem;
        if (n < 50) {
            float bia = b1a[n];
            #pragma unroll
            for (int mi = 0; mi < 4; ++mi)
                #pragma unroll
                for (int r = 0; r < 4; ++r)
                    h1[(mi * 16 + kq * 4 + r) * H1S + n] =
                        fmaxf(acc[mi][r] + bia, 0.0f);
        }
    }
    BAR();                 // h1 ready

    // ---- tail: every thread does full layer2/3 + score for token = lane
    // (4 waves redundant; no further barriers)
    const float* h1r = (const float*)smem + lane * H1S;

    float h2[20];
    #pragma unroll
    for (int o = 0; o < 20; ++o) h2[o] = b1b[o];
    #pragma unroll
    for (int i = 0; i < 50; ++i) {
        float hv = h1r[i];
        #pragma unroll
        for (int o = 0; o < 20; ++o) h2[o] = fmaf(hv, W1b[o * 50 + i], h2[o]);
    }
    #pragma unroll
    for (int o = 0; o < 20; ++o) h2[o] = fmaxf(h2[o], 0.0f);

    float h3[20];
    #pragma unroll
    for (int o = 0; o < 20; ++o) {
        float a = b1c[o];
        const float* w = W1c + o * 20;
        #pragma unroll
        for (int i = 0; i < 20; ++i) a = fmaf(h2[i], w[i], a);
        h3[o] = fmaxf(a, 0.0f);
    }

    float s = pb2[0];
    #pragma unroll
    for (int j = 0; j < 10; ++j) {
        float a = pb1[j];
        const float* w = pW1 + j * 20;
        #pragma unroll
        for (int i = 0; i < 20; ++i) a = fmaf(h3[i], w[i], a);
        s = fmaf(fmaxf(a, 0.0f), pW2[j], s);
    }

    // softmax partial over this slab's 64 tokens
    float m = s;
    #pragma unroll
    for (int d = 32; d > 0; d >>= 1) m = fmaxf(m, __shfl_xor(m, d));
    float e = expf(s - m);
    float S = e;
    #pragma unroll
    for (int d = 32; d > 0; d >>= 1) S += __shfl_xor(S, d);

    float V[20];
    #pragma unroll
    for (int o = 0; o < 20; ++o) {
        float v = e * h3[o];
        #pragma unroll
        for (int d = 32; d > 0; d >>= 1) v += __shfl_xor(v, d);
        V[o] = v;
    }

    if (wv == 0) {
        float myv = m;
        if (lane == 1) myv = S;
        #pragma unroll
        for (int o = 0; o < 20; ++o) if (lane == o + 2) myv = V[o];
        if (lane < 22) partials[(size_t)blockIdx.x * 24 + lane] = myv;
    }
}

// ---------------------------------------------------------------------------
// Kernel B: combine half-group partials, pool over G=128, normalize, head.
// ---------------------------------------------------------------------------
__global__ __launch_bounds__(128, 4)
void pool_g_head(const float* __restrict__ partials,
                 const float* __restrict__ qW1, const float* __restrict__ qb1,
                 const float* __restrict__ qW2, const float* __restrict__ qb2,
                 const float* __restrict__ W3a, const float* __restrict__ b3a,
                 const float* __restrict__ W3b, const float* __restrict__ b3b,
                 float* __restrict__ out)
{
    __shared__ float red_m[2];
    __shared__ float red_s[2];
    __shared__ float part[2][20];

    const int tid = threadIdx.x;      // g
    const int b = blockIdx.x;
    const float* P = partials + ((size_t)(b * 128 + tid)) * 48;

    float m0 = P[0], S0 = P[1], m1 = P[24], S1 = P[25];
    float m = fmaxf(m0, m1);
    float w0 = expf(m0 - m), w1 = expf(m1 - m);
    float den = fmaf(S0, w0, S1 * w1);

    float v[20];
    #pragma unroll
    for (int o = 0; o < 20; ++o)
        v[o] = fmaf(P[2 + o], w0, P[26 + o] * w1) / den;

    float s = qb2[0];
    #pragma unroll
    for (int j = 0; j < 10; ++j) {
        float a = qb1[j];
        const float* w = qW1 + j * 20;
        #pragma unroll
        for (int i = 0; i < 20; ++i) a = fmaf(v[i], w[i], a);
        s = fmaf(fmaxf(a, 0.0f), qW2[j], s);
    }

    const int wig = tid >> 6, lane = tid & 63;
    float mm = s;
    #pragma unroll
    for (int d = 32; d > 0; d >>= 1) mm = fmaxf(mm, __shfl_xor(mm, d));
    if (lane == 0) red_m[wig] = mm;
    __syncthreads();
    mm = fmaxf(red_m[0], red_m[1]);

    float e = expf(s - mm);
    float su = e;
    #pragma unroll
    for (int d = 32; d > 0; d >>= 1) su += __shfl_xor(su, d);
    if (lane == 0) red_s[wig] = su;

    #pragma unroll
    for (int o = 0; o < 20; ++o) {
        float val = e * v[o];
        #pragma unroll
        for (int d = 32; d > 0; d >>= 1) val += __shfl_xor(val, d);
        if (lane == 0) part[wig][o] = val;
    }
    __syncthreads();

    if (tid == 0) {
        float dg = red_s[0] + red_s[1];
        float rb[20];
        float n2 = 0.0f;
        #pragma unroll
        for (int o = 0; o < 20; ++o) {
            rb[o] = (part[0][o] + part[1][o]) / dg;
            n2 = fmaf(rb[o], rb[o], n2);
        }
        float nrm = fmaxf(sqrtf(n2), 1e-12f);
        #pragma unroll
        for (int o = 0; o < 20; ++o) rb[o] /= nrm;

        float accv = b3b[0];
        #pragma unroll
        for (int j = 0; j < 10; ++j) {
            float a = b3a[j];
            const float* w = W3a + j * 20;
            #pragma unroll
            for (int i = 0; i < 20; ++i) a = fmaf(rb[i], w[i], a);
            accv = fmaf(fmaxf(a, 0.0f), W3b[j], accv);
        }
        out[b] = accv;
    }
}

extern "C" void kernel_launch(void* const* d_in, const int* in_sizes, int n_in,
                              void* d_out, int out_size, void* d_ws, size_t ws_size,
                              hipStream_t stream) {
    const float* x   = (const float*)d_in[0];
    const float* W1a = (const float*)d_in[1];
    const float* b1a = (const float*)d_in[2];
    const float* W1b = (const float*)d_in[3];
    const float* b1b = (const float*)d_in[4];
    const float* W1c = (const float*)d_in[5];
    const float* b1c = (const float*)d_in[6];
    const float* pW1 = (const float*)d_in[7];
    const float* pb1 = (const float*)d_in[8];
    const float* pW2 = (const float*)d_in[9];
    const float* pb2 = (const float*)d_in[10];
    const float* qW1 = (const float*)d_in[11];
    const float* qb1 = (const float*)d_in[12];
    const float* qW2 = (const float*)d_in[13];
    const float* qb2 = (const float*)d_in[14];
    const float* W3a = (const float*)d_in[15];
    const float* b3a = (const float*)d_in[16];
    const float* W3b = (const float*)d_in[17];
    const float* b3b = (const float*)d_in[18];

    float* partials      = (float*)d_ws;                             // 786,432 B
    unsigned short* Bpre = (unsigned short*)((char*)d_ws + 786432);  // 81,920 B

    prep_w<<<160, 256, 0, stream>>>(W1a, Bpre);
    fused_mlp<<<8192, 256, 0, stream>>>(
        x, Bpre, b1a, W1b, b1b, W1c, b1c, pW1, pb1, pW2, pb2, partials);
    pool_g_head<<<32, 128, 0, stream>>>(
        partials, qW1, qb1, qW2, qb2, W3a, b3a, W3b, b3b, (float*)d_out);
}